// Round 3
// baseline (143.538 us; speedup 1.0000x reference)
//
#include <hip/hip_runtime.h>

// Problem constants
#define B_ 4
#define C_ 64
#define F_ 64
#define T_ 128
#define IC_ 32
#define N_ 8192
#define M_ 2048

// Scratch layout (float units; all fp32 intermediates)
#define OFF_U      0            // B*N   = 32768   u[b][n] = t_score + a[n]
#define OFF_PSI2   32768        // B*M*IC = 262144 psi pooled, layout [b][m][c]
#define OFF_V      294912      // B*M   = 8192    v[b][m] = p_score - bpos
#define OFF_VS     303104      // B*M   sorted v (descending)
#define OFF_Q0     311296      // B*2049*64 = 524544  prefix of z, layout [b][k][o]
#define OFF_Q1     835840      // B*2049*64           prefix of v*z
#define WS_FLOATS  1360384     // 5.44 MB — static device global, NOT d_ws

// Static device scratch: allocated at module load, independent of ws_size.
// Fully rewritten on every kernel_launch call (no cross-call state).
__device__ __align__(16) float g_ws[WS_FLOATS];
__device__ int g_perm[B_ * M_];   // rank-sort permutation (separate array: no aliasing)

// ---------------------------------------------------------------------------
// Kernel 1: psi/phi conv + 2x2 maxpool, v[b,m], u[b,n]
// grid: B*32*2 = 256 blocks, 256 threads. block = (b, fh, t-chunk of 32 half-cols)
// ---------------------------------------------------------------------------
__global__ __launch_bounds__(256) void k_front(
    const float* __restrict__ x,
    const float* __restrict__ psi_w, const float* __restrict__ psi_b,
    const float* __restrict__ theta_w, const float* __restrict__ theta_b,
    const float* __restrict__ phi_w, const float* __restrict__ phi_b,
    const float* __restrict__ h0_w, const float* __restrict__ h1_w,
    const float* __restrict__ h2_w)
{
    float* __restrict__ ws = g_ws;
    __shared__ __align__(16) float xs[64 * 128];   // [c][r(2)][tl(64)]
    __shared__ float pw[32 * 65];                  // pitch 65: conflict-free over o
    __shared__ float fw[32 * 65];
    __shared__ float wt_l[64];

    const int tid = threadIdx.x;
    const int bid = blockIdx.x;
    const int b = bid >> 6;
    const int rem = bid & 63;
    const int fh = rem >> 1;
    const int tc = rem & 1;
    const int t0 = tc * 64;

    // stage x tile: channels 64 x rows {2fh,2fh+1} x cols [t0, t0+64)
    for (int idx = tid; idx < 8192; idx += 256) {
        int c = idx >> 7, r2 = (idx >> 6) & 1, tl = idx & 63;
        xs[idx] = x[(((size_t)b * 64 + c) * 64 + (2 * fh + r2)) * 128 + t0 + tl];
    }
    // stage weights (pitch 65)
    for (int idx = tid; idx < 2048; idx += 256) {
        int o = idx >> 6, c = idx & 63;
        pw[o * 65 + c] = psi_w[idx];
        fw[o * 65 + c] = phi_w[idx];
    }
    // collapsed theta head: wt[c] = sum_o h0[o]*theta_w[o,c]
    if (tid < 64) {
        float acc = 0.f;
        for (int o2 = 0; o2 < 32; ++o2)
            acc += h0_w[o2] * theta_w[o2 * 64 + tid];
        wt_l[tid] = acc;
    }
    __syncthreads();

    const float h20 = h2_w[0], h21 = h2_w[1];

    // ---- psi/phi conv + pool: thread = (o in [0,32), g in [0,8)), 4 passes over 32 half-cols
    {
        const int o = tid & 31, g = tid >> 5;
        const float pb = psi_b[o], fb = phi_b[o], h1 = h1_w[o];
        for (int p = 0; p < 4; ++p) {
            const int thl = p * 8 + g;          // half-col within chunk
            const int tb2 = 2 * thl;
            float sp0 = 0, sp1 = 0, sp2 = 0, sp3 = 0;
            float sf0 = 0, sf1 = 0, sf2 = 0, sf3 = 0;
            for (int c = 0; c < 64; ++c) {
                const float pwv = pw[o * 65 + c];
                const float fwv = fw[o * 65 + c];
                const float2 xa = *(const float2*)&xs[c * 128 + tb2];       // row 0
                const float2 xb = *(const float2*)&xs[c * 128 + 64 + tb2];  // row 1
                sp0 += pwv * xa.x; sp1 += pwv * xa.y; sp2 += pwv * xb.x; sp3 += pwv * xb.y;
                sf0 += fwv * xa.x; sf1 += fwv * xa.y; sf2 += fwv * xb.x; sf3 += fwv * xb.y;
            }
            const float psiv = fmaxf(fmaxf(sp0, sp1), fmaxf(sp2, sp3)) + pb;
            const float phiv = fmaxf(fmaxf(sf0, sf1), fmaxf(sf2, sf3)) + fb;
            const int m = fh * 64 + tc * 32 + thl;
            ws[OFF_PSI2 + ((size_t)b * 2048 + m) * 32 + o] = psiv;  // [b][m][c] coalesced
            // v[b,m] = sum_o h1[o]*phi - bpos ; butterfly over the 32 o-lanes
            float tv = h1 * phiv;
            for (int mask = 1; mask < 32; mask <<= 1)
                tv += __shfl_xor(tv, mask, 64);
            if (o == 0) {
                const float bpos = h20 * (fh * (1.0f / 31.0f))
                                 + h21 * ((tc * 32 + thl) * (1.0f / 63.0f));
                ws[OFF_V + b * 2048 + m] = tv - bpos;
            }
        }
    }

    // ---- u[b,n] for the 128 full positions in this tile
    if (tid < 128) {
        const int r2 = tid >> 6, tl = tid & 63;
        float acc = 0.f;
        for (int c = 0; c < 64; ++c)
            acc += xs[c * 128 + r2 * 64 + tl] * wt_l[c];
        float tb_ = 0.f;
        for (int o2 = 0; o2 < 32; ++o2)
            tb_ += h0_w[o2] * theta_b[o2];
        const int f = 2 * fh + r2, tt = t0 + tl;
        const int n = f * 128 + tt;
        const float a = h20 * (f * (1.0f / 63.0f)) + h21 * (tt * (1.0f / 127.0f));
        ws[OFF_U + b * 8192 + n] = acc + tb_ + a;
    }
}

// ---------------------------------------------------------------------------
// Kernel 2: barrier-free rank sort of v per batch (descending, index tie-break)
// grid: B*32 = 128 blocks, 256 threads. block = (b, chunk of 64 m's); each
// thread counts over a quarter of the j range; 4 partials summed in LDS.
// ---------------------------------------------------------------------------
__global__ __launch_bounds__(256) void k_rank()
{
    float* __restrict__ ws = g_ws;
    __shared__ __align__(16) float vl[2048];
    __shared__ int part[256];
    const int tid = threadIdx.x;
    const int b = blockIdx.x >> 5, chunk = blockIdx.x & 31;
    const float* v = ws + OFF_V + b * 2048;
    for (int i = tid; i < 2048; i += 256) vl[i] = v[i];
    __syncthreads();

    const int ml = tid & 63, jq = tid >> 6;
    const int m = chunk * 64 + ml;
    const float vm = vl[m];
    int cnt = 0;
    const float4* v4 = (const float4*)vl;
    const int j0 = jq * 128;                 // 128 float4 = 512 floats per quarter
    for (int j4 = j0; j4 < j0 + 128; ++j4) {
        const float4 vv = v4[j4];
        const int jb = j4 * 4;
        cnt += (vv.x > vm) || (vv.x == vm && (jb    ) < m);
        cnt += (vv.y > vm) || (vv.y == vm && (jb + 1) < m);
        cnt += (vv.z > vm) || (vv.z == vm && (jb + 2) < m);
        cnt += (vv.w > vm) || (vv.w == vm && (jb + 3) < m);
    }
    part[tid] = cnt;
    __syncthreads();
    if (tid < 64) {
        const int r = part[tid] + part[tid + 64] + part[tid + 128] + part[tid + 192];
        ws[OFF_VS + b * 2048 + r] = vm;
        g_perm[b * 2048 + r] = m;
    }
}

// ---------------------------------------------------------------------------
// Kernel 3: z = W_w[o,:] . psi (in sorted order), block scan -> Q0/Q1[b][k][o]
// grid: B*64 = 256 blocks (b,o), 256 threads; each thread handles 8 sorted i's
// ---------------------------------------------------------------------------
__global__ __launch_bounds__(256) void k_scan(
    const float* __restrict__ W_w)
{
    float* __restrict__ ws = g_ws;
    __shared__ float Wrow[32];
    __shared__ float a0[256], a1[256];
    const int tid = threadIdx.x;
    const int b = blockIdx.x >> 6, o = blockIdx.x & 63;
    if (tid < 32) Wrow[tid] = W_w[o * 33 + tid];   // W_w is (64, IC+1=33); col 32 = zero channel
    __syncthreads();

    const int* perm = g_perm + b * 2048;
    const float* vs = ws + OFF_VS + b * 2048;
    const float* psi2 = ws + OFF_PSI2 + (size_t)b * 2048 * 32;

    float zl[8], vlv[8];
    float s0 = 0.f, s1 = 0.f;
    const int base = tid * 8;
    for (int q = 0; q < 8; ++q) {
        const int i = base + q;
        const int mp = perm[i];
        const float4* pr = (const float4*)(psi2 + (size_t)mp * 32);
        float z = 0.f;
#pragma unroll
        for (int w = 0; w < 8; ++w) {
            const float4 p4 = pr[w];
            z += Wrow[4 * w] * p4.x + Wrow[4 * w + 1] * p4.y
               + Wrow[4 * w + 2] * p4.z + Wrow[4 * w + 3] * p4.w;
        }
        const float vv = vs[i];
        zl[q] = z; vlv[q] = vv;
        s0 += z; s1 += vv * z;
    }
    // block inclusive scan of per-thread sums (Hillis-Steele in LDS)
    a0[tid] = s0; a1[tid] = s1;
    __syncthreads();
    for (int off = 1; off < 256; off <<= 1) {
        const float t0_ = (tid >= off) ? a0[tid - off] : 0.f;
        const float t1_ = (tid >= off) ? a1[tid - off] : 0.f;
        __syncthreads();
        a0[tid] += t0_; a1[tid] += t1_;
        __syncthreads();
    }
    float r0 = a0[tid] - s0, r1 = a1[tid] - s1;  // exclusive base
    float* Q0 = ws + OFF_Q0 + (size_t)b * 2049 * 64;
    float* Q1 = ws + OFF_Q1 + (size_t)b * 2049 * 64;
    for (int q = 0; q < 8; ++q) {
        r0 += zl[q]; r1 += vlv[q] * zl[q];
        Q0[(size_t)(base + q + 1) * 64 + o] = r0;
        Q1[(size_t)(base + q + 1) * 64 + o] = r1;
    }
    if (tid == 0) { Q0[o] = 0.f; Q1[o] = 0.f; }
}

// ---------------------------------------------------------------------------
// Kernel 4: per (b, 64-n tile): binary search k(n), gather Q rows, fold
// W_b + BN, transpose through LDS, add x, store fp32.
// grid: B*128 = 512 blocks, 256 threads
// ---------------------------------------------------------------------------
__global__ __launch_bounds__(256) void k_out(
    const float* __restrict__ x,
    const float* __restrict__ W_b,
    const float* __restrict__ bn_g, const float* __restrict__ bn_b,
    const float* __restrict__ bn_m, const float* __restrict__ bn_v,
    float* __restrict__ out)
{
    const float* __restrict__ ws = g_ws;
    __shared__ float vsl[2048];
    __shared__ float tileb[64 * 65];   // [o][n], pitch 65
    __shared__ int karr[64];
    __shared__ float uarr[64];

    const int tid = threadIdx.x;
    const int b = blockIdx.x >> 7, tile = blockIdx.x & 127;
    const int n0 = tile * 64;

    const float* vs = ws + OFF_VS + b * 2048;
    for (int i = tid; i < 2048; i += 256) vsl[i] = vs[i];
    __syncthreads();

    if (tid < 64) {
        const float u = ws[OFF_U + b * 8192 + n0 + tid];
        const float thr = -u;
        int lo = 0, hi = 2048;
        while (lo < hi) {                 // first idx with vs[idx] <= -u (descending)
            const int mid = (lo + hi) >> 1;
            if (vsl[mid] > thr) lo = mid + 1; else hi = mid;
        }
        karr[tid] = lo;
        uarr[tid] = u;
    }
    __syncthreads();

    const int lane = tid & 63, w = tid >> 6;
    const float inv = bn_g[lane] * __frsqrt_rn(bn_v[lane] + 1e-5f);
    const float sft = W_b[lane] * inv + bn_b[lane] - bn_m[lane] * inv;
    const float* Q0 = ws + OFF_Q0 + (size_t)b * 2049 * 64;
    const float* Q1 = ws + OFF_Q1 + (size_t)b * 2049 * 64;

    for (int nl = w; nl < 64; nl += 4) {
        const int k = karr[nl];
        const float u = uarr[nl];
        const float q0 = Q0[(size_t)k * 64 + lane];   // 256B coalesced row
        const float q1 = Q1[(size_t)k * 64 + lane];
        const float raw = (u * q0 + q1) * (1.0f / 2048.0f);
        tileb[lane * 65 + nl] = raw * inv + sft;
    }
    __syncthreads();

    for (int idx = tid; idx < 4096; idx += 256) {
        const int o = idx >> 6, j = idx & 63;
        const size_t gi = ((size_t)b * 64 + o) * 8192 + n0 + j;
        out[gi] = tileb[o * 65 + j] + x[gi];
    }
}

// ---------------------------------------------------------------------------
extern "C" void kernel_launch(void* const* d_in, const int* in_sizes, int n_in,
                              void* d_out, int out_size, void* d_ws, size_t ws_size,
                              hipStream_t stream)
{
    (void)in_sizes; (void)n_in; (void)out_size; (void)d_ws; (void)ws_size;
    const float* x       = (const float*)d_in[0];
    const float* psi_w   = (const float*)d_in[1];
    const float* psi_b   = (const float*)d_in[2];
    const float* theta_w = (const float*)d_in[3];
    const float* theta_b = (const float*)d_in[4];
    const float* phi_w   = (const float*)d_in[5];
    const float* phi_b   = (const float*)d_in[6];
    const float* h0_w    = (const float*)d_in[7];
    const float* h1_w    = (const float*)d_in[8];
    const float* h2_w    = (const float*)d_in[9];
    const float* W_w     = (const float*)d_in[10];
    const float* W_b     = (const float*)d_in[11];
    const float* bn_g    = (const float*)d_in[12];
    const float* bn_b    = (const float*)d_in[13];
    const float* bn_m    = (const float*)d_in[14];
    const float* bn_v    = (const float*)d_in[15];
    float* out = (float*)d_out;

    k_front<<<dim3(256), dim3(256), 0, stream>>>(x, psi_w, psi_b, theta_w, theta_b,
                                                 phi_w, phi_b, h0_w, h1_w, h2_w);
    k_rank<<<dim3(128), dim3(256), 0, stream>>>();
    k_scan<<<dim3(256), dim3(256), 0, stream>>>(W_w);
    k_out<<<dim3(512), dim3(256), 0, stream>>>(x, W_b, bn_g, bn_b, bn_m, bn_v, out);
}

// Round 4
// 137.447 us; speedup vs baseline: 1.0443x; 1.0443x over previous
//
#include <hip/hip_runtime.h>

// Problem constants
#define B_ 4
#define C_ 64
#define F_ 64
#define T_ 128
#define IC_ 32
#define N_ 8192
#define M_ 2048

// Scratch layout (float units; all fp32 intermediates)
#define OFF_U      0            // B*N   = 32768   u[b][n]
#define OFF_PSI2   32768        // B*M*IC = 262144 psi pooled, layout [b][m][c]
#define OFF_V      294912      // B*M
#define OFF_VS     303104      // B*M   sorted v (descending)
#define OFF_Q0     311296      // B*2049*64 prefix of z, layout [b][k][o]
#define OFF_Q1     835840      // B*2049*64 prefix of v*z
#define WS_FLOATS  1360384     // 5.44 MB static device scratch (d_ws too small to trust)

__device__ __align__(16) float g_ws[WS_FLOATS];
__device__ int g_perm[B_ * M_];

// ---------------------------------------------------------------------------
// Kernel 1: psi/phi conv + 2x2 maxpool, v[b,m], u[b,n]
// grid: B*32*4 = 512 blocks, 256 threads. block = (b, fh, col-quarter of 32 cols)
// LDS ~33KB -> 2 blocks/CU (grid-bound) = 8 waves/CU
// ---------------------------------------------------------------------------
__global__ __launch_bounds__(256) void k_front(
    const float* __restrict__ x,
    const float* __restrict__ psi_w, const float* __restrict__ psi_b,
    const float* __restrict__ theta_w, const float* __restrict__ theta_b,
    const float* __restrict__ phi_w, const float* __restrict__ phi_b,
    const float* __restrict__ h0_w, const float* __restrict__ h1_w,
    const float* __restrict__ h2_w)
{
    float* __restrict__ ws = g_ws;
    __shared__ __align__(16) float xs[64 * 64];    // [c][r2(2)][col(32)]
    __shared__ float pw[32 * 65];                  // pitch 65: conflict-free
    __shared__ float fw[32 * 65];
    __shared__ float wt_l[64];

    const int tid = threadIdx.x;
    const int bid = blockIdx.x;
    const int b = bid >> 7;
    const int rem = bid & 127;
    const int fh = rem >> 2;        // [0,32)
    const int q = rem & 3;          // col-quarter [0,4)
    const int c0 = q * 32;          // first col of this tile

    // stage x tile: 64 ch x rows {2fh,2fh+1} x cols [c0, c0+32)
    for (int idx = tid; idx < 4096; idx += 256) {
        int c = idx >> 6, r2 = (idx >> 5) & 1, tl = idx & 31;
        xs[idx] = x[(((size_t)b * 64 + c) * 64 + (2 * fh + r2)) * 128 + c0 + tl];
    }
    for (int idx = tid; idx < 2048; idx += 256) {
        int o = idx >> 6, c = idx & 63;
        pw[o * 65 + c] = psi_w[idx];
        fw[o * 65 + c] = phi_w[idx];
    }
    if (tid < 64) {
        float acc = 0.f;
        for (int o2 = 0; o2 < 32; ++o2)
            acc += h0_w[o2] * theta_w[o2 * 64 + tid];
        wt_l[tid] = acc;
    }
    __syncthreads();

    const float h20 = h2_w[0], h21 = h2_w[1];

    // ---- conv + pool: thread = (o in [0,32), g in [0,8)); handles half-cols g and g+8
    {
        const int o = tid & 31, g = tid >> 5;
        const float pb = psi_b[o], fb = phi_b[o], h1 = h1_w[o];
        float sp[2][4] = {{0,0,0,0},{0,0,0,0}};
        float sf[2][4] = {{0,0,0,0},{0,0,0,0}};
        const int hc0 = g, hc1 = g + 8;            // half-cols within tile [0,16)
        for (int c = 0; c < 64; ++c) {
            const float pwv = pw[o * 65 + c];
            const float fwv = fw[o * 65 + c];
            const float2 xa0 = *(const float2*)&xs[c * 64 + 2 * hc0];
            const float2 xb0 = *(const float2*)&xs[c * 64 + 32 + 2 * hc0];
            const float2 xa1 = *(const float2*)&xs[c * 64 + 2 * hc1];
            const float2 xb1 = *(const float2*)&xs[c * 64 + 32 + 2 * hc1];
            sp[0][0] += pwv * xa0.x; sp[0][1] += pwv * xa0.y;
            sp[0][2] += pwv * xb0.x; sp[0][3] += pwv * xb0.y;
            sf[0][0] += fwv * xa0.x; sf[0][1] += fwv * xa0.y;
            sf[0][2] += fwv * xb0.x; sf[0][3] += fwv * xb0.y;
            sp[1][0] += pwv * xa1.x; sp[1][1] += pwv * xa1.y;
            sp[1][2] += pwv * xb1.x; sp[1][3] += pwv * xb1.y;
            sf[1][0] += fwv * xa1.x; sf[1][1] += fwv * xa1.y;
            sf[1][2] += fwv * xb1.x; sf[1][3] += fwv * xb1.y;
        }
#pragma unroll
        for (int h = 0; h < 2; ++h) {
            const int hc = h ? hc1 : hc0;
            const float psiv = fmaxf(fmaxf(sp[h][0], sp[h][1]), fmaxf(sp[h][2], sp[h][3])) + pb;
            const float phiv = fmaxf(fmaxf(sf[h][0], sf[h][1]), fmaxf(sf[h][2], sf[h][3])) + fb;
            const int m = fh * 64 + q * 16 + hc;
            ws[OFF_PSI2 + ((size_t)b * 2048 + m) * 32 + o] = psiv;
            float tv = h1 * phiv;
            for (int mask = 1; mask < 32; mask <<= 1)
                tv += __shfl_xor(tv, mask, 64);
            if (o == 0) {
                const float bpos = h20 * (fh * (1.0f / 31.0f))
                                 + h21 * ((q * 16 + hc) * (1.0f / 63.0f));
                ws[OFF_V + b * 2048 + m] = tv - bpos;
            }
        }
    }

    // ---- u[b,n] for the 64 full positions of this tile
    if (tid < 64) {
        const int r2 = tid >> 5, tl = tid & 31;
        float acc = 0.f;
        for (int c = 0; c < 64; ++c)
            acc += xs[c * 64 + r2 * 32 + tl] * wt_l[c];
        float tb_ = 0.f;
        for (int o2 = 0; o2 < 32; ++o2)
            tb_ += h0_w[o2] * theta_b[o2];
        const int f = 2 * fh + r2, tt = c0 + tl;
        const int n = f * 128 + tt;
        const float a = h20 * (f * (1.0f / 63.0f)) + h21 * (tt * (1.0f / 127.0f));
        ws[OFF_U + b * 8192 + n] = acc + tb_ + a;
    }
}

// ---------------------------------------------------------------------------
// Kernel 2: barrier-free rank sort (descending, index tie-break)
// grid: B*128 = 512 blocks, 256 threads. block = (b, chunk of 16 m's);
// thread = (jq in [0,16) segment of 128 j's) x (ml in [0,16)).
// ---------------------------------------------------------------------------
__global__ __launch_bounds__(256) void k_rank()
{
    float* __restrict__ ws = g_ws;
    __shared__ __align__(16) float vl[2048];
    __shared__ int part[256];
    const int tid = threadIdx.x;
    const int b = blockIdx.x >> 7, chunk = blockIdx.x & 127;
    const float* v = ws + OFF_V + b * 2048;
    for (int i = tid; i < 2048; i += 256) vl[i] = v[i];
    __syncthreads();

    const int ml = tid & 15, jq = tid >> 4;
    const int m = chunk * 16 + ml;
    const float vm = vl[m];
    int cnt = 0;
    const float4* v4 = (const float4*)vl;
    const int j0 = jq * 32;                 // 32 float4 = 128 floats per segment
    for (int j4 = j0; j4 < j0 + 32; ++j4) {
        const float4 vv = v4[j4];
        const int jb = j4 * 4;
        cnt += (vv.x > vm) || (vv.x == vm && (jb    ) < m);
        cnt += (vv.y > vm) || (vv.y == vm && (jb + 1) < m);
        cnt += (vv.z > vm) || (vv.z == vm && (jb + 2) < m);
        cnt += (vv.w > vm) || (vv.w == vm && (jb + 3) < m);
    }
    part[tid] = cnt;
    __syncthreads();
    if (tid < 16) {
        int r = 0;
#pragma unroll
        for (int j = 0; j < 16; ++j) r += part[j * 16 + tid];
        ws[OFF_VS + b * 2048 + r] = vl[chunk * 16 + tid];
        g_perm[b * 2048 + r] = chunk * 16 + tid;
    }
}

// ---------------------------------------------------------------------------
// Kernel 3: z = W_w[o,:] . psi (sorted order), block scan -> Q0/Q1[b][k][o]
// grid: B*64 = 256 blocks (b,o), 512 threads (8 waves/CU); 4 items/thread
// ---------------------------------------------------------------------------
__global__ __launch_bounds__(512) void k_scan(
    const float* __restrict__ W_w)
{
    float* __restrict__ ws = g_ws;
    __shared__ float Wrow[32];
    __shared__ float a0[512], a1[512];
    const int tid = threadIdx.x;
    const int b = blockIdx.x >> 6, o = blockIdx.x & 63;
    if (tid < 32) Wrow[tid] = W_w[o * 33 + tid];   // W_w is (64,33); col 32 = zero channel
    __syncthreads();

    const int* perm = g_perm + b * 2048;
    const float* vs = ws + OFF_VS + b * 2048;
    const float* psi2 = ws + OFF_PSI2 + (size_t)b * 2048 * 32;

    float zl[4], vlv[4];
    float s0 = 0.f, s1 = 0.f;
    const int base = tid * 4;
#pragma unroll
    for (int qq = 0; qq < 4; ++qq) {
        const int i = base + qq;
        const int mp = perm[i];
        const float4* pr = (const float4*)(psi2 + (size_t)mp * 32);
        float z = 0.f;
#pragma unroll
        for (int w = 0; w < 8; ++w) {
            const float4 p4 = pr[w];
            z += Wrow[4 * w] * p4.x + Wrow[4 * w + 1] * p4.y
               + Wrow[4 * w + 2] * p4.z + Wrow[4 * w + 3] * p4.w;
        }
        const float vv = vs[i];
        zl[qq] = z; vlv[qq] = vv;
        s0 += z; s1 += vv * z;
    }
    a0[tid] = s0; a1[tid] = s1;
    __syncthreads();
    for (int off = 1; off < 512; off <<= 1) {
        const float t0_ = (tid >= off) ? a0[tid - off] : 0.f;
        const float t1_ = (tid >= off) ? a1[tid - off] : 0.f;
        __syncthreads();
        a0[tid] += t0_; a1[tid] += t1_;
        __syncthreads();
    }
    float r0 = a0[tid] - s0, r1 = a1[tid] - s1;  // exclusive base
    float* Q0 = ws + OFF_Q0 + (size_t)b * 2049 * 64;
    float* Q1 = ws + OFF_Q1 + (size_t)b * 2049 * 64;
#pragma unroll
    for (int qq = 0; qq < 4; ++qq) {
        r0 += zl[qq]; r1 += vlv[qq] * zl[qq];
        Q0[(size_t)(base + qq + 1) * 64 + o] = r0;
        Q1[(size_t)(base + qq + 1) * 64 + o] = r1;
    }
    if (tid == 0) { Q0[o] = 0.f; Q1[o] = 0.f; }
}

// ---------------------------------------------------------------------------
// Kernel 4: per (b, 64-n tile): binary search k(n) in L2, gather Q rows,
// fold W_b + BN, transpose through LDS (pitch 65), add x, store.
// grid: B*128 = 512 blocks, 512 threads (16 waves/CU)
// ---------------------------------------------------------------------------
__global__ __launch_bounds__(512) void k_out(
    const float* __restrict__ x,
    const float* __restrict__ W_b,
    const float* __restrict__ bn_g, const float* __restrict__ bn_b,
    const float* __restrict__ bn_m, const float* __restrict__ bn_v,
    float* __restrict__ out)
{
    const float* __restrict__ ws = g_ws;
    __shared__ float tileb[64 * 65];   // [o][n], pitch 65
    __shared__ int karr[64];
    __shared__ float uarr[64];

    const int tid = threadIdx.x;
    const int b = blockIdx.x >> 7, tile = blockIdx.x & 127;
    const int n0 = tile * 64;

    const float* vs = ws + OFF_VS + b * 2048;
    if (tid < 64) {
        const float u = ws[OFF_U + b * 8192 + n0 + tid];
        const float thr = -u;
        int lo = 0, hi = 2048;
        while (lo < hi) {                 // first idx with vs[idx] <= -u (descending)
            const int mid = (lo + hi) >> 1;
            if (vs[mid] > thr) lo = mid + 1; else hi = mid;
        }
        karr[tid] = lo;
        uarr[tid] = u;
    }
    __syncthreads();

    const int lane = tid & 63, w = tid >> 6;   // w in [0,8)
    const float inv = bn_g[lane] * __frsqrt_rn(bn_v[lane] + 1e-5f);
    const float sft = W_b[lane] * inv + bn_b[lane] - bn_m[lane] * inv;
    const float* Q0 = ws + OFF_Q0 + (size_t)b * 2049 * 64;
    const float* Q1 = ws + OFF_Q1 + (size_t)b * 2049 * 64;

    for (int nl = w; nl < 64; nl += 8) {
        const int k = karr[nl];
        const float u = uarr[nl];
        const float q0 = Q0[(size_t)k * 64 + lane];   // 256B coalesced row
        const float q1 = Q1[(size_t)k * 64 + lane];
        const float raw = (u * q0 + q1) * (1.0f / 2048.0f);
        tileb[lane * 65 + nl] = raw * inv + sft;      // bank (lane+nl)%32: 2-way, free
    }
    __syncthreads();

    for (int idx = tid; idx < 2048; idx += 512) {     // float2 epilogue
        const int o = idx >> 5, j2 = idx & 31;
        const size_t gi = ((size_t)b * 64 + o) * 8192 + n0 + 2 * j2;
        const float2 xv = *(const float2*)&x[gi];
        float2 r;
        r.x = tileb[o * 65 + 2 * j2] + xv.x;
        r.y = tileb[o * 65 + 2 * j2 + 1] + xv.y;
        *(float2*)&out[gi] = r;
    }
}

// ---------------------------------------------------------------------------
extern "C" void kernel_launch(void* const* d_in, const int* in_sizes, int n_in,
                              void* d_out, int out_size, void* d_ws, size_t ws_size,
                              hipStream_t stream)
{
    (void)in_sizes; (void)n_in; (void)out_size; (void)d_ws; (void)ws_size;
    const float* x       = (const float*)d_in[0];
    const float* psi_w   = (const float*)d_in[1];
    const float* psi_b   = (const float*)d_in[2];
    const float* theta_w = (const float*)d_in[3];
    const float* theta_b = (const float*)d_in[4];
    const float* phi_w   = (const float*)d_in[5];
    const float* phi_b   = (const float*)d_in[6];
    const float* h0_w    = (const float*)d_in[7];
    const float* h1_w    = (const float*)d_in[8];
    const float* h2_w    = (const float*)d_in[9];
    const float* W_w     = (const float*)d_in[10];
    const float* W_b     = (const float*)d_in[11];
    const float* bn_g    = (const float*)d_in[12];
    const float* bn_b    = (const float*)d_in[13];
    const float* bn_m    = (const float*)d_in[14];
    const float* bn_v    = (const float*)d_in[15];
    float* out = (float*)d_out;

    k_front<<<dim3(512), dim3(256), 0, stream>>>(x, psi_w, psi_b, theta_w, theta_b,
                                                 phi_w, phi_b, h0_w, h1_w, h2_w);
    k_rank<<<dim3(512), dim3(256), 0, stream>>>();
    k_scan<<<dim3(256), dim3(512), 0, stream>>>(W_w);
    k_out<<<dim3(512), dim3(512), 0, stream>>>(x, W_b, bn_g, bn_b, bn_m, bn_v, out);
}